// Round 11
// baseline (61.646 us; speedup 1.0000x reference)
//
#include <hip/hip_runtime.h>

// CompositionTransform  B=2, C=3, D=128, H=160, W=160, range_flow=0.4
// out[b,c,d,h,w] = trilerp_border(flow_2[b,c], (w,h,d)+rf*flow_1[b,:,d,h,w]) + flow_1[b,c,d,h,w]
//
// R10 = R8 (best: 44.0us) + non-temporal hints. Evidence: rocprof replays run
//     ~2x bench dur (serialization) -> real utilizations ~2x counters: HBM
//     ~3.75 TB/s (60% achievable) is the top pipe. Footprint 235MB vs 256MB L3:
//     output write-allocation evicts inputs. nt stores (out) + nt loads (f1,
//     single-use) keep L3 for f2 (the only reused stream).
//     Everything else identical to R8: tile 32x8x4, slab 64x12x8=24KB (PX=64 ->
//     bank=rx), 6 blocks/CU, DMA staging, 3 channel phases, ok-mask fallback.

constexpr int DD = 128, HH = 160, WW = 160;
constexpr int HW = HH * WW;              // 25600
constexpr int SP = DD * HW;              // 3276800
constexpr int TX = 32, TH = 8, TD = 4;   // output tile: 32x8x4, 4 outputs/thread (d)
constexpr int PX = 64, PY = 12, PZ = 8;  // staged slab; PX%32==0 -> bank = rx only
constexpr int PHF = PX * PY * PZ;        // 6144 dwords = 24 KB
constexpr int RUNS = PHF / 4 / 256;      // 6 staging runs/thread, exact
constexpr int NTX = WW / TX, NTH = HH / TH, NTD = DD / TD; // 5,20,32
constexpr int NB = 2 * NTX * NTH * NTD;  // 6400 blocks (mult of 8)

#define AS1 __attribute__((address_space(1)))
#define AS3 __attribute__((address_space(3)))

__global__ __launch_bounds__(256, 6) void comp_xform_nt(
    const float* __restrict__ f1,
    const float* __restrict__ f2,
    const float* __restrict__ rfp,
    float* __restrict__ out)
{
    __shared__ __align__(16) float slab[PHF];   // 24576 B -> 6 blocks/CU

    const int tid = threadIdx.x;

    // XCD-chunked bijective swizzle (NB % 8 == 0)
    const int bid = blockIdx.x;
    const int wg  = (bid & 7) * (NB / 8) + (bid >> 3);

    const int tx = wg % NTX; int r_ = wg / NTX;
    const int th = r_ % NTH; r_ /= NTH;
    const int td = r_ % NTD; const int b = r_ / NTD;

    const int x0 = tx * TX, h0 = th * TH, d0 = td * TD;
    const int xlo = x0 - 4, ylo = h0 - 2, zlo = d0 - 2;

    const size_t boff = (size_t)b * (size_t)(3 * SP);
    const float* __restrict__ f1b = f1 + boff;
    const float* __restrict__ f2b = f2 + boff;
    float* __restrict__ ob = out + boff;

    const float rf = rfp[0];

    const int wl = tid & 31, hh = tid >> 5;
    const int w = x0 + wl, h = h0 + hh;
    const int sp0 = (d0 * HH + h) * WW + w;
    const int wbase = tid & 192;             // wave-uniform float4-slot base

    // ---- staging source offsets (same for all 3 channels), 16 runs/row ----
    int goff[RUNS];
#pragma unroll
    for (int r = 0; r < RUNS; ++r) {
        const int s = r * 256 + tid;
        const int row = s >> 4, k = s & 15;            // 16 float4-runs per 64-dword row
        const int rz = row / PY, ry = row - rz * PY;
        const int gz = min(max(zlo + rz, 0), DD - 1);
        const int gy = min(max(ylo + ry, 0), HH - 1);
        const int gx = min(max(xlo + 4 * k, 0), WW - 4);
        goff[r] = (gz * HH + gy) * WW + gx;
    }

    // DMA stage: channel src -> slab (wave-uniform LDS base + lane*16)
    auto stage = [&](const float* __restrict__ src) {
#pragma unroll
        for (int r = 0; r < RUNS; ++r) {
            const float* gp = src + goff[r];
            AS3 void* lp = (AS3 void*)&slab[(r * 256 + wbase) * 4];
            __builtin_amdgcn_global_load_lds((const AS1 void*)gp, lp, 16, 0, 0);
        }
    };

    // ---- stage channel 0 immediately ----
    stage(f2b);

    // ---- flow_1: issue all 12 loads, non-temporal (single-use stream) ----
    float f1s0[TD], f1s1[TD], f1s2[TD];
#pragma unroll
    for (int dd = 0; dd < TD; ++dd) {
        const int sp = sp0 + dd * HW;
        f1s0[dd] = __builtin_nontemporal_load(f1b + sp);
        f1s1[dd] = __builtin_nontemporal_load(f1b + SP + sp);
        f1s2[dd] = __builtin_nontemporal_load(f1b + 2 * SP + sp);
    }

    // ---- positions, slab offsets, weights; ok-mask for outliers ----
    int voff[TD]; float wxs[TD], wys[TD], wzs[TD]; unsigned okm = 0;
#pragma unroll
    for (int dd = 0; dd < TD; ++dd) {
        const float x = fminf(fmaxf((float)w + rf * f1s0[dd], 0.f), (float)(WW - 1));
        const float y = fminf(fmaxf((float)h + rf * f1s1[dd], 0.f), (float)(HH - 1));
        const float z = fminf(fmaxf((float)(d0 + dd) + rf * f1s2[dd], 0.f), (float)(DD - 1));
        const float fx = floorf(x), fy = floorf(y), fz = floorf(z);
        const int rx = (int)fx - xlo, ry = (int)fy - ylo, rz = (int)fz - zlo;
        const bool ok = ((unsigned)rx <= 38u) & ((unsigned)ry <= 10u) & ((unsigned)rz <= 6u);
        okm |= (ok ? 1u : 0u) << dd;
        voff[dd] = ok ? ((rz * PY + ry) * PX + rx) : 0;
        wxs[dd] = ok ? (x - fx) : x;     // fallback lanes stash raw coords
        wys[dd] = ok ? (y - fy) : y;
        wzs[dd] = ok ? (z - fz) : z;
    }

    __syncthreads();   // vmcnt(0) + barrier: slab (ch0) ready

#pragma unroll
    for (int c = 0; c < 3; ++c) {
        const float* __restrict__ br  = slab;
        const float* __restrict__ f2c = f2b + (size_t)c * SP;   // fallback source
        float* __restrict__ oc = ob + (size_t)c * SP;

#pragma unroll
        for (int dd = 0; dd < TD; ++dd) {
            const float* p = br + voff[dd];
            const float wx = wxs[dd], wy = wys[dd], wz = wzs[dd];
            const float ax = 1.f - wx, ay = 1.f - wy, az = 1.f - wz;
            const float a0 = p[0],            a1 = p[1];
            const float b0 = p[PX],           b1 = p[PX + 1];
            const float c0 = p[PX * PY],      c1 = p[PX * PY + 1];
            const float e0 = p[PX * PY + PX], e1 = p[PX * PY + PX + 1];
            const float top = ay * fmaf(a0, ax, a1 * wx) + wy * fmaf(b0, ax, b1 * wx);
            const float bot = ay * fmaf(c0, ax, c1 * wx) + wy * fmaf(e0, ax, e1 * wx);
            const float res = az * top + wz * bot;
            const float f1c = (c == 0) ? f1s0[dd] : ((c == 1) ? f1s1[dd] : f1s2[dd]);
            __builtin_nontemporal_store(res + f1c, oc + sp0 + dd * HW);
        }

        // rare exact fallback (|displacement|>2); whole wave skips via exec-z
        if (okm != 15u) {
#pragma unroll
            for (int dd = 0; dd < TD; ++dd) {
                if (!((okm >> dd) & 1u)) {
                    const float X = wxs[dd], Y = wys[dd], Z = wzs[dd];
                    const float fx = floorf(X), fy = floorf(Y), fz = floorf(Z);
                    const float wx = X - fx, wy = Y - fy, wz = Z - fz;
                    const int ix0 = (int)fx, iy0 = (int)fy, iz0 = (int)fz;
                    const int ix1 = min(ix0 + 1, WW - 1);
                    const int iy1 = min(iy0 + 1, HH - 1);
                    const int iz1 = min(iz0 + 1, DD - 1);
                    const int q00 = (iz0 * HH + iy0) * WW, q01 = (iz0 * HH + iy1) * WW;
                    const int q10 = (iz1 * HH + iy0) * WW, q11 = (iz1 * HH + iy1) * WW;
                    const float c000 = f2c[q00 + ix0], c001 = f2c[q00 + ix1];
                    const float c010 = f2c[q01 + ix0], c011 = f2c[q01 + ix1];
                    const float c100 = f2c[q10 + ix0], c101 = f2c[q10 + ix1];
                    const float c110 = f2c[q11 + ix0], c111 = f2c[q11 + ix1];
                    const float ax = 1.f - wx, ay = 1.f - wy, az = 1.f - wz;
                    const float top = ay * (c000 * ax + c001 * wx) + wy * (c010 * ax + c011 * wx);
                    const float bot = ay * (c100 * ax + c101 * wx) + wy * (c110 * ax + c111 * wx);
                    const float f1c = (c == 0) ? f1s0[dd] : ((c == 1) ? f1s1[dd] : f1s2[dd]);
                    __builtin_nontemporal_store(az * top + wz * bot + f1c, oc + sp0 + dd * HW);
                }
            }
        }

        // stage next channel into the (single) slab between barriers
        if (c < 2) {
            __syncthreads();                       // all waves done reading
            stage(f2b + (size_t)(c + 1) * SP);
            __syncthreads();                       // slab (c+1) ready
        }
    }
}

extern "C" void kernel_launch(void* const* d_in, const int* in_sizes, int n_in,
                              void* d_out, int out_size, void* d_ws, size_t ws_size,
                              hipStream_t stream) {
    const float* f1  = (const float*)d_in[0];
    const float* f2  = (const float*)d_in[1];
    // d_in[2] = sample_grid (identity meshgrid) — unused by construction
    const float* rfp = (const float*)d_in[3];
    float* out = (float*)d_out;

    comp_xform_nt<<<NB, 256, 0, stream>>>(f1, f2, rfp, out);
}

// Round 12
// 43.899 us; speedup vs baseline: 1.4043x; 1.4043x over previous
//
#include <hip/hip_runtime.h>

// CompositionTransform  B=2, C=3, D=128, H=160, W=160, range_flow=0.4
// out[b,c,d,h,w] = trilerp_border(flow_2[b,c], (w,h,d)+rf*flow_1[b,:,d,h,w]) + flow_1[b,c,d,h,w]
//
// R11 = R8 exact revert (best measured: 44.0us) minus R10's nt hints (store-path
//     cache bypass throttled HBM: 44->62us, falsified) plus one zero-risk VALU
//     trim: the x-component of staging offsets (k = tid&15) is invariant across
//     the 6 runs -> hoisted out of the loop (~24 prologue ops/thread saved).
//     Axes bracketed across R1-R10: occupancy 20/37/60% (+-3%), barriers 1/3/5
//     (+-3%), bank conflicts 2.5/5/8M (+-3%), reg-staging vs DMA (DMA wins),
//     bf16 pack (loses), dbuf (loses), nt (loses). Traffic is at the mandatory
//     floor (165MB vs 157MB: f1-read + out-write; f2 ~fully L3-served).

constexpr int DD = 128, HH = 160, WW = 160;
constexpr int HW = HH * WW;              // 25600
constexpr int SP = DD * HW;              // 3276800
constexpr int TX = 32, TH = 8, TD = 4;   // output tile: 32x8x4, 4 outputs/thread (d)
constexpr int PX = 64, PY = 12, PZ = 8;  // staged slab; PX%32==0 -> bank = rx only
constexpr int PHF = PX * PY * PZ;        // 6144 dwords = 24 KB
constexpr int RUNS = PHF / 4 / 256;      // 6 staging runs/thread, exact
constexpr int NTX = WW / TX, NTH = HH / TH, NTD = DD / TD; // 5,20,32
constexpr int NB = 2 * NTX * NTH * NTD;  // 6400 blocks (mult of 8)

#define AS1 __attribute__((address_space(1)))
#define AS3 __attribute__((address_space(3)))

__global__ __launch_bounds__(256, 6) void comp_xform_r11(
    const float* __restrict__ f1,
    const float* __restrict__ f2,
    const float* __restrict__ rfp,
    float* __restrict__ out)
{
    __shared__ __align__(16) float slab[PHF];   // 24576 B -> 6 blocks/CU

    const int tid = threadIdx.x;

    // XCD-chunked bijective swizzle (NB % 8 == 0)
    const int bid = blockIdx.x;
    const int wg  = (bid & 7) * (NB / 8) + (bid >> 3);

    const int tx = wg % NTX; int r_ = wg / NTX;
    const int th = r_ % NTH; r_ /= NTH;
    const int td = r_ % NTD; const int b = r_ / NTD;

    const int x0 = tx * TX, h0 = th * TH, d0 = td * TD;
    const int xlo = x0 - 4, ylo = h0 - 2, zlo = d0 - 2;

    const size_t boff = (size_t)b * (size_t)(3 * SP);
    const float* __restrict__ f1b = f1 + boff;
    const float* __restrict__ f2b = f2 + boff;
    float* __restrict__ ob = out + boff;

    const float rf = rfp[0];

    const int wl = tid & 31, hh = tid >> 5;
    const int w = x0 + wl, h = h0 + hh;
    const int sp0 = (d0 * HH + h) * WW + w;
    const int wbase = tid & 192;             // wave-uniform float4-slot base

    // ---- staging source offsets; x-component is per-thread invariant ----
    const int gx = min(max(xlo + 4 * (tid & 15), 0), WW - 4);   // hoisted (R11)
    const int row0 = tid >> 4;                                   // row = row0 + 16r
    int goff[RUNS];
#pragma unroll
    for (int r = 0; r < RUNS; ++r) {
        const int row = row0 + 16 * r;
        const int rz = row / PY, ry = row - rz * PY;
        const int gz = min(max(zlo + rz, 0), DD - 1);
        const int gy = min(max(ylo + ry, 0), HH - 1);
        goff[r] = (gz * HH + gy) * WW + gx;
    }

    // DMA stage: channel src -> slab (wave-uniform LDS base + lane*16)
    auto stage = [&](const float* __restrict__ src) {
#pragma unroll
        for (int r = 0; r < RUNS; ++r) {
            const float* gp = src + goff[r];
            AS3 void* lp = (AS3 void*)&slab[(r * 256 + wbase) * 4];
            __builtin_amdgcn_global_load_lds((const AS1 void*)gp, lp, 16, 0, 0);
        }
    };

    // ---- stage channel 0 immediately ----
    stage(f2b);

    // ---- flow_1: issue all 12 loads (overlaps the DMA) ----
    float f1s0[TD], f1s1[TD], f1s2[TD];
#pragma unroll
    for (int dd = 0; dd < TD; ++dd) {
        const int sp = sp0 + dd * HW;
        f1s0[dd] = f1b[sp];
        f1s1[dd] = f1b[SP + sp];
        f1s2[dd] = f1b[2 * SP + sp];
    }

    // ---- positions, slab offsets, weights; ok-mask for outliers ----
    int voff[TD]; float wxs[TD], wys[TD], wzs[TD]; unsigned okm = 0;
#pragma unroll
    for (int dd = 0; dd < TD; ++dd) {
        const float x = fminf(fmaxf((float)w + rf * f1s0[dd], 0.f), (float)(WW - 1));
        const float y = fminf(fmaxf((float)h + rf * f1s1[dd], 0.f), (float)(HH - 1));
        const float z = fminf(fmaxf((float)(d0 + dd) + rf * f1s2[dd], 0.f), (float)(DD - 1));
        const float fx = floorf(x), fy = floorf(y), fz = floorf(z);
        const int rx = (int)fx - xlo, ry = (int)fy - ylo, rz = (int)fz - zlo;
        const bool ok = ((unsigned)rx <= 38u) & ((unsigned)ry <= 10u) & ((unsigned)rz <= 6u);
        okm |= (ok ? 1u : 0u) << dd;
        voff[dd] = ok ? ((rz * PY + ry) * PX + rx) : 0;
        wxs[dd] = ok ? (x - fx) : x;     // fallback lanes stash raw coords
        wys[dd] = ok ? (y - fy) : y;
        wzs[dd] = ok ? (z - fz) : z;
    }

    __syncthreads();   // vmcnt(0) + barrier: slab (ch0) ready

#pragma unroll
    for (int c = 0; c < 3; ++c) {
        const float* __restrict__ br  = slab;
        const float* __restrict__ f2c = f2b + (size_t)c * SP;   // fallback source
        float* __restrict__ oc = ob + (size_t)c * SP;

#pragma unroll
        for (int dd = 0; dd < TD; ++dd) {
            const float* p = br + voff[dd];
            const float wx = wxs[dd], wy = wys[dd], wz = wzs[dd];
            const float ax = 1.f - wx, ay = 1.f - wy, az = 1.f - wz;
            const float a0 = p[0],            a1 = p[1];
            const float b0 = p[PX],           b1 = p[PX + 1];
            const float c0 = p[PX * PY],      c1 = p[PX * PY + 1];
            const float e0 = p[PX * PY + PX], e1 = p[PX * PY + PX + 1];
            const float top = ay * fmaf(a0, ax, a1 * wx) + wy * fmaf(b0, ax, b1 * wx);
            const float bot = ay * fmaf(c0, ax, c1 * wx) + wy * fmaf(e0, ax, e1 * wx);
            const float res = az * top + wz * bot;
            const float f1c = (c == 0) ? f1s0[dd] : ((c == 1) ? f1s1[dd] : f1s2[dd]);
            oc[sp0 + dd * HW] = res + f1c;
        }

        // rare exact fallback (|displacement|>2); whole wave skips via exec-z
        if (okm != 15u) {
#pragma unroll
            for (int dd = 0; dd < TD; ++dd) {
                if (!((okm >> dd) & 1u)) {
                    const float X = wxs[dd], Y = wys[dd], Z = wzs[dd];
                    const float fx = floorf(X), fy = floorf(Y), fz = floorf(Z);
                    const float wx = X - fx, wy = Y - fy, wz = Z - fz;
                    const int ix0 = (int)fx, iy0 = (int)fy, iz0 = (int)fz;
                    const int ix1 = min(ix0 + 1, WW - 1);
                    const int iy1 = min(iy0 + 1, HH - 1);
                    const int iz1 = min(iz0 + 1, DD - 1);
                    const int q00 = (iz0 * HH + iy0) * WW, q01 = (iz0 * HH + iy1) * WW;
                    const int q10 = (iz1 * HH + iy0) * WW, q11 = (iz1 * HH + iy1) * WW;
                    const float c000 = f2c[q00 + ix0], c001 = f2c[q00 + ix1];
                    const float c010 = f2c[q01 + ix0], c011 = f2c[q01 + ix1];
                    const float c100 = f2c[q10 + ix0], c101 = f2c[q10 + ix1];
                    const float c110 = f2c[q11 + ix0], c111 = f2c[q11 + ix1];
                    const float ax = 1.f - wx, ay = 1.f - wy, az = 1.f - wz;
                    const float top = ay * (c000 * ax + c001 * wx) + wy * (c010 * ax + c011 * wx);
                    const float bot = ay * (c100 * ax + c101 * wx) + wy * (c110 * ax + c111 * wx);
                    const float f1c = (c == 0) ? f1s0[dd] : ((c == 1) ? f1s1[dd] : f1s2[dd]);
                    oc[sp0 + dd * HW] = az * top + wz * bot + f1c;
                }
            }
        }

        // stage next channel into the (single) slab between barriers
        if (c < 2) {
            __syncthreads();                       // all waves done reading
            stage(f2b + (size_t)(c + 1) * SP);
            __syncthreads();                       // slab (c+1) ready
        }
    }
}

extern "C" void kernel_launch(void* const* d_in, const int* in_sizes, int n_in,
                              void* d_out, int out_size, void* d_ws, size_t ws_size,
                              hipStream_t stream) {
    const float* f1  = (const float*)d_in[0];
    const float* f2  = (const float*)d_in[1];
    // d_in[2] = sample_grid (identity meshgrid) — unused by construction
    const float* rfp = (const float*)d_in[3];
    float* out = (float*)d_out;

    comp_xform_r11<<<NB, 256, 0, stream>>>(f1, f2, rfp, out);
}